// Round 6
// baseline (620.850 us; speedup 1.0000x reference)
//
#include <hip/hip_runtime.h>
#include <stdint.h>
#include <stddef.h>

#define DEVFN __device__ __forceinline__

typedef float f32x4 __attribute__((ext_vector_type(4)));
typedef long i64_t;

constexpr int T_TOK = 4096, H_DIM = 2048, I_DIM = 1408;
constexpr int N_EXP = 8;
constexpr int P_PAIRS = T_TOK * 2;     // 8192 routed pairs
constexpr int BM = 64;                 // rows per tile
constexpr int MAXT = 144;              // >= sum ceil(cnt_e/64) <= 136
constexpr int GU_ROWS = 2 * I_DIM;     // 2816

// ---- workspace layout (bytes) ----
// NOTE: harness delivers fp8 tensors as f32 VALUES (dtype fallback), so we
// convert weights to fp8 bytes in ws first.
constexpr size_t OFF_WGU = 0;                                          // fp8 gup [E][2I][H]
constexpr size_t OFF_WD  = OFF_WGU + (size_t)N_EXP * GU_ROWS * H_DIM;  // fp8 down [E][H][I]
constexpr size_t OFF_XQ  = OFF_WD + (size_t)N_EXP * H_DIM * I_DIM;     // fp8 act quant [T][H]
constexpr size_t OFF_XS  = OFF_XQ + (size_t)T_TOK * H_DIM;             // f32 act scales [T][16]
constexpr size_t OFF_IQ  = OFF_XS + (size_t)T_TOK * 16 * 4;            // fp8 inter quant [P+64][I]
constexpr size_t OFF_IS  = OFF_IQ + (size_t)(P_PAIRS + BM) * I_DIM;    // f32 inter scales [P][11]
constexpr size_t OFF_PS  = OFF_IS + (size_t)P_PAIRS * 11 * 4;          // pairs_sorted [P]
constexpr size_t OFF_PP  = OFF_PS + (size_t)P_PAIRS * 4;               // pos_of_pair [P]
constexpr size_t OFF_TE  = OFF_PP + (size_t)P_PAIRS * 4;               // tile expert
constexpr size_t OFF_TR  = OFF_TE + (size_t)MAXT * 4;                  // tile row start
constexpr size_t OFF_TM  = OFF_TR + (size_t)MAXT * 4;                  // tile rows
constexpr size_t OFF_Y   = (OFF_TM + (size_t)MAXT * 4 + 255) & ~(size_t)255;
constexpr size_t NEED_Y  = OFF_Y + (size_t)P_PAIRS * H_DIM * 4;        // y scratch [P][H] f32

// ---- exact RNE f32 -> OCP e4m3fn (input must be clamped to [-448,448], finite) ----
DEVFN unsigned f32_to_e4m3(float x) {
  unsigned u = __float_as_uint(x);
  unsigned s = (u >> 24) & 0x80u;
  int e = (int)((u >> 23) & 0xffu);
  unsigned m = u & 0x7fffffu;
  if (e == 0) return s;                 // fp32 zero/subnormal -> 0
  int ef = e - 127;
  if (ef < -10) return s;               // below half of min subnormal -> 0
  unsigned mant = 0x800000u | m;        // 1.m, 24 bits
  int shift = (ef < -6) ? (14 - ef) : 20;   // 21..24 for subnormal, 20 normal
  int e8 = (ef < -6) ? 0 : (ef + 7);
  unsigned keep = mant >> shift;
  unsigned rmask = 1u << (shift - 1);
  unsigned rbit = (mant & rmask) ? 1u : 0u;
  unsigned sticky = (mant & (rmask - 1u)) ? 1u : 0u;
  keep += (rbit & (sticky | (keep & 1u)));
  if (e8 == 0) {
    if (keep >= 8u) { e8 = 1; keep -= 8u; }
  } else {
    if (keep >= 16u) { keep >>= 1; e8 += 1; }
    keep -= 8u;
  }
  return s | ((unsigned)e8 << 3) | keep;
}

DEVFN float clampq(float v) { return fminf(fmaxf(v, -448.f), 448.f); }

DEVFN void gll(const uint8_t* g, uint8_t* l) {
  __builtin_amdgcn_global_load_lds((const __attribute__((address_space(1))) void*)g,
                                   (__attribute__((address_space(3))) void*)l,
                                   16, 0, 0);
}

// ---------------- weight convert: f32(values are exact fp8) -> fp8 bytes ----------------
__global__ __launch_bounds__(256) void k_wq(const float* __restrict__ wf,
                                            uint8_t* __restrict__ wq, int n4) {
  int i = blockIdx.x * 256 + threadIdx.x;
  if (i >= n4) return;
  float4 v = *(const float4*)(wf + (size_t)i * 4);
  unsigned b = f32_to_e4m3(clampq(v.x)) | (f32_to_e4m3(clampq(v.y)) << 8) |
               (f32_to_e4m3(clampq(v.z)) << 16) | (f32_to_e4m3(clampq(v.w)) << 24);
  *(unsigned*)(wq + (size_t)i * 4) = b;
}

// ---------------- activation quant: x[T][H] f32 -> xq fp8, xs f32[T][16] ----------------
__global__ __launch_bounds__(256) void k_actq(const float* __restrict__ x,
                                              uint8_t* __restrict__ xq,
                                              float* __restrict__ xs) {
  int t = blockIdx.x, tid = threadIdx.x;
  const float* row = x + (size_t)t * H_DIM + tid * 8;
  float4 v0 = *(const float4*)(row);
  float4 v1 = *(const float4*)(row + 4);
  float vals[8] = {v0.x, v0.y, v0.z, v0.w, v1.x, v1.y, v1.z, v1.w};
  float am = 0.f;
#pragma unroll
  for (int j = 0; j < 8; ++j) am = fmaxf(am, fabsf(vals[j]));
#pragma unroll
  for (int d = 1; d < 16; d <<= 1) am = fmaxf(am, __shfl_xor(am, d, 64));
  float s = fmaxf(am, 1e-12f) / 448.0f;
  if ((tid & 15) == 0) xs[(size_t)t * 16 + (tid >> 4)] = s;
  unsigned lo = 0, hi = 0;
#pragma unroll
  for (int j = 0; j < 4; ++j) lo |= f32_to_e4m3(clampq(vals[j] / s)) << (8 * j);
#pragma unroll
  for (int j = 0; j < 4; ++j) hi |= f32_to_e4m3(clampq(vals[4 + j] / s)) << (8 * j);
  uint2 pk; pk.x = lo; pk.y = hi;
  *(uint2*)(xq + (size_t)t * H_DIM + tid * 8) = pk;
}

// ---------------- routing: bucket pairs per expert, build tile table ----------------
__global__ __launch_bounds__(256) void k_route(const int* __restrict__ tki,
                                               int* __restrict__ ps, int* __restrict__ pp,
                                               int* __restrict__ te, int* __restrict__ tr,
                                               int* __restrict__ tm) {
  __shared__ int cnt[8], off[9], cur[8];
  int tid = threadIdx.x;
  if (tid < 8) cnt[tid] = 0;
  __syncthreads();
  for (int p = tid; p < P_PAIRS; p += 256) atomicAdd(&cnt[tki[p]], 1);
  __syncthreads();
  if (tid == 0) {
    int a = 0;
    for (int e = 0; e < 8; ++e) { off[e] = a; cur[e] = a; a += cnt[e]; }
    off[8] = a;
  }
  __syncthreads();
  for (int p = tid; p < P_PAIRS; p += 256) {
    int pos = atomicAdd(&cur[tki[p]], 1);
    ps[pos] = p;
    pp[p] = pos;
  }
  __syncthreads();
  if (tid == 0) {
    int nt = 0;
    for (int e = 0; e < 8; ++e)
      for (int s = off[e]; s < off[e + 1]; s += BM) {
        int rem = off[e + 1] - s;
        te[nt] = e; tr[nt] = s; tm[nt] = rem < BM ? rem : BM; ++nt;
      }
    for (; nt < MAXT; ++nt) { te[nt] = -1; tr[nt] = 0; tm[nt] = 0; }
  }
}

// ---------------- GEMM1: h = xq @ gate_up^T (fp8 MFMA, blockwise scales); fused silu*up + inter quant ----------------
__global__ __launch_bounds__(256) void k_gemm1(
    const uint8_t* __restrict__ xq, const float* __restrict__ xs,
    const uint8_t* __restrict__ gup, const float* __restrict__ gsf,
    const int* __restrict__ te, const int* __restrict__ tr, const int* __restrict__ tm,
    const int* __restrict__ ps,
    uint8_t* __restrict__ iq, float* __restrict__ isv) {
  __shared__ uint8_t smA[BM * 128];
  __shared__ uint8_t smBg[128 * 128];
  __shared__ uint8_t smBu[128 * 128];
  __shared__ __align__(16) float smSa[BM];
  __shared__ float smRed[2][2][32];

  const int bx = blockIdx.x;
  const int e = te[bx];
  if (e < 0) return;
  const int r0 = tr[bx], mrows = tm[bx];
  const int n0 = blockIdx.y * 128;
  const int nbg = blockIdx.y;
  const int tid = threadIdx.x;
  const int lane = tid & 63;
  const int wid = tid >> 6;
  const int wm = wid >> 1, wn = wid & 1;
  const int lrow = lane & 15, lgrp = lane >> 4;
  const int mbase = wm * 32;
  const int wb = wid * 1024;

  // staging source pointers (pre-swizzled source, linear LDS dest)
  const int m0 = tid >> 3, m1 = m0 + 32;
  const int kcol = (tid & 7) * 16;
  const int srcOff = kcol ^ ((m0 & 7) << 4);   // m1&7 == m0&7
  const int t0 = (m0 < mrows) ? (ps[r0 + m0] >> 1) : 0;
  const int t1 = (m1 < mrows) ? (ps[r0 + m1] >> 1) : 0;
  const uint8_t* pA0 = xq + (size_t)t0 * H_DIM + srcOff;
  const uint8_t* pA1 = xq + (size_t)t1 * H_DIM + srcOff;
  const uint8_t* pBg = gup + ((size_t)e * GU_ROWS + n0 + m0) * H_DIM + srcOff;
  const uint8_t* pBu = pBg + (size_t)I_DIM * H_DIM;
  int tS = 0;
  if (tid < 64) tS = (tid < mrows) ? (ps[r0 + tid] >> 1) : 0;
  const float* xsrow = xs + (size_t)tS * 16;

  // fragment LDS addresses
  const int swz = (lrow & 7) << 4;
  int koff[4];
#pragma unroll
  for (int kk = 0; kk < 4; ++kk) koff[kk] = ((kk * 32 + lgrp * 8) ^ swz);
  const uint8_t* pAf[2];
  pAf[0] = smA + (mbase + lrow) * 128;
  pAf[1] = smA + (mbase + 16 + lrow) * 128;
  const uint8_t* pBf[4];
#pragma unroll
  for (int nf = 0; nf < 4; ++nf) pBf[nf] = smBg + (wn * 64 + nf * 16 + lrow) * 128;
  const ptrdiff_t dBu = smBu - smBg;

  const float* sfg = gsf + ((size_t)e * 22 + nbg) * 16;
  const float* sfu = gsf + ((size_t)e * 22 + 11 + nbg) * 16;

  f32x4 accg[2][4], accu[2][4];
#pragma unroll
  for (int mf = 0; mf < 2; ++mf)
#pragma unroll
    for (int nf = 0; nf < 4; ++nf) { accg[mf][nf] = 0.f; accu[mf][nf] = 0.f; }

  for (int ks = 0; ks < 16; ++ks) {
    __syncthreads();
    gll(pA0, smA + wb);
    gll(pA1, smA + 4096 + wb);
#pragma unroll
    for (int c = 0; c < 4; ++c) {
      gll(pBg + (size_t)c * (32 * H_DIM), smBg + c * 4096 + wb);
      gll(pBu + (size_t)c * (32 * H_DIM), smBu + c * 4096 + wb);
    }
    if (tid < 64) smSa[tid] = xsrow[ks];
    __syncthreads();

    i64_t a[2][4];
#pragma unroll
    for (int mf = 0; mf < 2; ++mf)
#pragma unroll
      for (int kk = 0; kk < 4; ++kk) a[mf][kk] = *(const i64_t*)(pAf[mf] + koff[kk]);
    f32x4 saf[2];
    saf[0] = *(const f32x4*)(smSa + mbase + lgrp * 4);
    saf[1] = *(const f32x4*)(smSa + mbase + 16 + lgrp * 4);
    float swg = sfg[ks], swu = sfu[ks];

#pragma unroll
    for (int half = 0; half < 2; ++half) {
      const ptrdiff_t ho = half ? dBu : 0;
      f32x4 part[2][4];
#pragma unroll
      for (int mf = 0; mf < 2; ++mf)
#pragma unroll
        for (int nf = 0; nf < 4; ++nf) part[mf][nf] = 0.f;
#pragma unroll
      for (int kk = 0; kk < 4; ++kk)
#pragma unroll
        for (int nf = 0; nf < 4; ++nf) {
          i64_t b = *(const i64_t*)(pBf[nf] + ho + koff[kk]);
          part[0][nf] = __builtin_amdgcn_mfma_f32_16x16x32_fp8_fp8(a[0][kk], b, part[0][nf], 0, 0, 0);
          part[1][nf] = __builtin_amdgcn_mfma_f32_16x16x32_fp8_fp8(a[1][kk], b, part[1][nf], 0, 0, 0);
        }
      float sw = half ? swu : swg;
      f32x4 (*acch)[4] = half ? accu : accg;
#pragma unroll
      for (int mf = 0; mf < 2; ++mf) {
        f32x4 sc = saf[mf] * sw;
#pragma unroll
        for (int nf = 0; nf < 4; ++nf) acch[mf][nf] += part[mf][nf] * sc;
      }
    }
    pA0 += 128; pA1 += 128; pBg += 128; pBu += 128;
  }

  // ---- epilogue: inter = silu(g)*u, per-row amax over 128 cols, exact fp8 quant ----
  float itv[2][4][4];
  float amx[2][4];
#pragma unroll
  for (int mf = 0; mf < 2; ++mf)
#pragma unroll
    for (int r = 0; r < 4; ++r) amx[mf][r] = 0.f;
#pragma unroll
  for (int mf = 0; mf < 2; ++mf)
#pragma unroll
    for (int nf = 0; nf < 4; ++nf)
#pragma unroll
      for (int r = 0; r < 4; ++r) {
        float g = accg[mf][nf][r], u = accu[mf][nf][r];
        float sg = 1.0f / (1.0f + expf(-g));
        float iv = g * sg * u;
        itv[mf][nf][r] = iv;
        amx[mf][r] = fmaxf(amx[mf][r], fabsf(iv));
      }
#pragma unroll
  for (int mf = 0; mf < 2; ++mf)
#pragma unroll
    for (int r = 0; r < 4; ++r)
#pragma unroll
      for (int d = 1; d < 16; d <<= 1) amx[mf][r] = fmaxf(amx[mf][r], __shfl_xor(amx[mf][r], d, 64));

  if (lrow == 0) {
#pragma unroll
    for (int mf = 0; mf < 2; ++mf)
#pragma unroll
      for (int r = 0; r < 4; ++r) smRed[wm][wn][mf * 16 + lgrp * 4 + r] = amx[mf][r];
  }
  __syncthreads();

#pragma unroll
  for (int mf = 0; mf < 2; ++mf)
#pragma unroll
    for (int r = 0; r < 4; ++r) {
      float am2 = fmaxf(amx[mf][r], smRed[wm][wn ^ 1][mf * 16 + lgrp * 4 + r]);
      float s = fmaxf(am2, 1e-12f) / 448.0f;
      int R = mbase + mf * 16 + lgrp * 4 + r;
      if (R < mrows) {
        if (wn == 0 && lrow == 0) isv[(size_t)(r0 + R) * 11 + nbg] = s;
        size_t rowb = (size_t)(r0 + R) * I_DIM + n0 + wn * 64 + lrow;
#pragma unroll
        for (int nf = 0; nf < 4; ++nf) {
          float v = clampq(itv[mf][nf][r] / s);
          iq[rowb + nf * 16] = (uint8_t)f32_to_e4m3(v);
        }
      }
    }
}

// ---------------- GEMM2: y = iq @ down^T, weighted write (y-scratch or atomic) ----------------
template <bool ATOMIC>
__global__ __launch_bounds__(256) void k_gemm2(
    const uint8_t* __restrict__ iq, const float* __restrict__ isv,
    const uint8_t* __restrict__ dp, const float* __restrict__ dsf,
    const int* __restrict__ te, const int* __restrict__ tr, const int* __restrict__ tm,
    const int* __restrict__ ps, const float* __restrict__ tkw,
    float* __restrict__ outy) {
  __shared__ uint8_t smA[BM * 128];
  __shared__ uint8_t smB[128 * 128];
  __shared__ __align__(16) float smSa[BM];

  const int bx = blockIdx.x;
  const int e = te[bx];
  if (e < 0) return;
  const int r0 = tr[bx], mrows = tm[bx];
  const int n0 = blockIdx.y * 128;
  const int tid = threadIdx.x;
  const int lane = tid & 63;
  const int wid = tid >> 6;
  const int wm = wid >> 1, wn = wid & 1;
  const int lrow = lane & 15, lgrp = lane >> 4;
  const int mbase = wm * 32;
  const int wb = wid * 1024;

  const int m0 = tid >> 3, m1 = m0 + 32;
  const int kcol = (tid & 7) * 16;
  const int srcOff = kcol ^ ((m0 & 7) << 4);
  const uint8_t* pA0 = iq + (size_t)(r0 + m0) * I_DIM + srcOff;
  const uint8_t* pA1 = iq + (size_t)(r0 + m1) * I_DIM + srcOff;
  const uint8_t* pB = dp + ((size_t)e * H_DIM + n0 + m0) * I_DIM + srcOff;

  const int swz = (lrow & 7) << 4;
  int koff[4];
#pragma unroll
  for (int kk = 0; kk < 4; ++kk) koff[kk] = ((kk * 32 + lgrp * 8) ^ swz);
  const uint8_t* pAf[2];
  pAf[0] = smA + (mbase + lrow) * 128;
  pAf[1] = smA + (mbase + 16 + lrow) * 128;
  const uint8_t* pBf[4];
#pragma unroll
  for (int nf = 0; nf < 4; ++nf) pBf[nf] = smB + (wn * 64 + nf * 16 + lrow) * 128;

  const float* sfd = dsf + ((size_t)e * 16 + blockIdx.y) * 11;

  f32x4 acc[2][4];
#pragma unroll
  for (int mf = 0; mf < 2; ++mf)
#pragma unroll
    for (int nf = 0; nf < 4; ++nf) acc[mf][nf] = 0.f;

  for (int ks = 0; ks < 11; ++ks) {
    __syncthreads();
    gll(pA0, smA + wb);
    gll(pA1, smA + 4096 + wb);
#pragma unroll
    for (int c = 0; c < 4; ++c) gll(pB + (size_t)c * (32 * I_DIM), smB + c * 4096 + wb);
    if (tid < 64) {
      float v = (tid < mrows) ? isv[(size_t)(r0 + tid) * 11 + ks] : 0.f;
      smSa[tid] = v;
    }
    __syncthreads();

    i64_t a[2][4];
#pragma unroll
    for (int mf = 0; mf < 2; ++mf)
#pragma unroll
      for (int kk = 0; kk < 4; ++kk) a[mf][kk] = *(const i64_t*)(pAf[mf] + koff[kk]);
    f32x4 saf[2];
    saf[0] = *(const f32x4*)(smSa + mbase + lgrp * 4);
    saf[1] = *(const f32x4*)(smSa + mbase + 16 + lgrp * 4);
    float sw = sfd[ks];

    f32x4 part[2][4];
#pragma unroll
    for (int mf = 0; mf < 2; ++mf)
#pragma unroll
      for (int nf = 0; nf < 4; ++nf) part[mf][nf] = 0.f;
#pragma unroll
    for (int kk = 0; kk < 4; ++kk)
#pragma unroll
      for (int nf = 0; nf < 4; ++nf) {
        i64_t b = *(const i64_t*)(pBf[nf] + koff[kk]);
        part[0][nf] = __builtin_amdgcn_mfma_f32_16x16x32_fp8_fp8(a[0][kk], b, part[0][nf], 0, 0, 0);
        part[1][nf] = __builtin_amdgcn_mfma_f32_16x16x32_fp8_fp8(a[1][kk], b, part[1][nf], 0, 0, 0);
      }
#pragma unroll
    for (int mf = 0; mf < 2; ++mf) {
      f32x4 sc = saf[mf] * sw;
#pragma unroll
      for (int nf = 0; nf < 4; ++nf) acc[mf][nf] += part[mf][nf] * sc;
    }
    pA0 += 128; pA1 += 128; pB += 128;
  }

#pragma unroll
  for (int mf = 0; mf < 2; ++mf)
#pragma unroll
    for (int r = 0; r < 4; ++r) {
      int R = mbase + mf * 16 + lgrp * 4 + r;
      if (R < mrows) {
        int prow = r0 + R;
        int p = ps[prow];
        float w = tkw[p];
        if (ATOMIC) {
          float* ob = outy + (size_t)(p >> 1) * H_DIM + n0 + wn * 64 + lrow;
#pragma unroll
          for (int nf = 0; nf < 4; ++nf) atomicAdd(ob + nf * 16, acc[mf][nf][r] * w);
        } else {
          float* ob = outy + (size_t)prow * H_DIM + n0 + wn * 64 + lrow;
#pragma unroll
          for (int nf = 0; nf < 4; ++nf) ob[nf * 16] = acc[mf][nf][r] * w;
        }
      }
    }
}

// ---------------- combine: out[t] = y[pos(t,0)] + y[pos(t,1)] (weights pre-applied) ----------------
__global__ __launch_bounds__(256) void k_combine(const float* __restrict__ y,
                                                 const int* __restrict__ pp,
                                                 float* __restrict__ out) {
  size_t g = (size_t)blockIdx.x * 256 + threadIdx.x;
  int t = (int)(g >> 9);
  int c = (int)(g & 511) * 4;
  int ra = pp[2 * t], rb = pp[2 * t + 1];
  float4 va = *(const float4*)(y + (size_t)ra * H_DIM + c);
  float4 vb = *(const float4*)(y + (size_t)rb * H_DIM + c);
  float4 vo;
  vo.x = va.x + vb.x; vo.y = va.y + vb.y; vo.z = va.z + vb.z; vo.w = va.w + vb.w;
  *(float4*)(out + (size_t)t * H_DIM + c) = vo;
}

extern "C" void kernel_launch(void* const* d_in, const int* in_sizes, int n_in,
                              void* d_out, int out_size, void* d_ws, size_t ws_size,
                              hipStream_t stream) {
  (void)in_sizes; (void)n_in; (void)out_size;
  const float* x = (const float*)d_in[0];
  const int* tki = (const int*)d_in[1];
  const float* tkw = (const float*)d_in[2];
  const float* gup_f = (const float*)d_in[3];   // fp8 values delivered as f32
  const float* gsf = (const float*)d_in[4];
  const float* dp_f = (const float*)d_in[5];    // fp8 values delivered as f32
  const float* dsf = (const float*)d_in[6];
  float* out = (float*)d_out;
  uint8_t* ws = (uint8_t*)d_ws;

  uint8_t* wgu = ws + OFF_WGU;
  uint8_t* wd = ws + OFF_WD;
  uint8_t* xq = ws + OFF_XQ;
  float* xs = (float*)(ws + OFF_XS);
  uint8_t* iq = ws + OFF_IQ;
  float* isv = (float*)(ws + OFF_IS);
  int* ps = (int*)(ws + OFF_PS);
  int* pp = (int*)(ws + OFF_PP);
  int* te = (int*)(ws + OFF_TE);
  int* tr = (int*)(ws + OFF_TR);
  int* tm = (int*)(ws + OFF_TM);
  float* y = (float*)(ws + OFF_Y);

  const int n4_gu = (N_EXP * GU_ROWS * H_DIM) / 4;   // 11,534,336
  const int n4_d = (N_EXP * H_DIM * I_DIM) / 4;      // 5,767,168
  k_wq<<<dim3((n4_gu + 255) / 256), dim3(256), 0, stream>>>(gup_f, wgu, n4_gu);
  k_wq<<<dim3((n4_d + 255) / 256), dim3(256), 0, stream>>>(dp_f, wd, n4_d);
  k_actq<<<dim3(T_TOK), dim3(256), 0, stream>>>(x, xq, xs);
  k_route<<<dim3(1), dim3(256), 0, stream>>>(tki, ps, pp, te, tr, tm);
  k_gemm1<<<dim3(MAXT, 11), dim3(256), 0, stream>>>(xq, xs, wgu, gsf, te, tr, tm, ps, iq, isv);
  if (ws_size >= NEED_Y) {
    k_gemm2<false><<<dim3(MAXT, 16), dim3(256), 0, stream>>>(iq, isv, wd, dsf, te, tr, tm, ps, tkw, y);
    k_combine<<<dim3((T_TOK * (H_DIM / 4)) / 256), dim3(256), 0, stream>>>(y, pp, out);
  } else {
    hipMemsetAsync(d_out, 0, (size_t)T_TOK * H_DIM * sizeof(float), stream);
    k_gemm2<true><<<dim3(MAXT, 16), dim3(256), 0, stream>>>(iq, isv, wd, dsf, te, tr, tm, ps, tkw, out);
  }
}